// Round 1
// baseline (764.026 us; speedup 1.0000x reference)
//
#include <hip/hip_runtime.h>
#include <stdint.h>

typedef unsigned short u16;
typedef __attribute__((ext_vector_type(8))) short short8;
typedef __attribute__((ext_vector_type(4))) float f32x4;

#define SEQ    2048
#define FEAT   3584
#define NHEAD  16
#define HD     256
#define WSLOT  917504  // 3584*256

static __device__ __forceinline__ float bf2f(u16 v){
  union { unsigned u; float f; } x; x.u = ((unsigned)v) << 16; return x.f;
}
static __device__ __forceinline__ u16 f2bf(float f){
  union { float f; unsigned u; } x; x.f = f;
  unsigned r = x.u + 0x7fffu + ((x.u >> 16) & 1u);
  return (u16)(r >> 16);
}

static __device__ __forceinline__ void gl_lds16(const u16* g, u16* l){
  __builtin_amdgcn_global_load_lds((const __attribute__((address_space(1))) void*)g,
                                   (__attribute__((address_space(3))) void*)l,
                                   16, 0, 0);
}

// ---------------- x f32 -> bf16 ----------------
__global__ void k_conv_x(const float* __restrict__ x, u16* __restrict__ xb){
  int i = (blockIdx.x * 256 + threadIdx.x) * 4;
  float4 v = *(const float4*)(x + i);
  ushort4 o; o.x = f2bf(v.x); o.y = f2bf(v.y); o.z = f2bf(v.z); o.w = f2bf(v.w);
  *(ushort4*)(xb + i) = o;
}

// ---------------- RoPE tables ----------------
__global__ void k_rope_tab(const int* __restrict__ sp, float* __restrict__ rc, float* __restrict__ rs){
  int idx = blockIdx.x * 256 + threadIdx.x;   // t*128 + i
  int t = idx >> 7, i = idx & 127;
  float ts = powf(10000.0f, (float)i * (1.0f / 128.0f));
  float ang = (float)sp[t] / ts;
  float s, c;
  sincosf(ang, &s, &c);
  rc[idx] = c; rs[idx] = s;
}

// ---------------- transpose + convert (f32 src -> bf16 dst, dst[c][r] = src[r][c]) ----------------
__global__ void k_tconv_f32(const float* __restrict__ src, u16* __restrict__ dst,
                            long sslot, long dslot, int sld, int dld){
  __shared__ u16 tile[64][68];
  src += (long)blockIdx.z * sslot;
  dst += (long)blockIdx.z * dslot;
  int r0 = blockIdx.y * 64, c0 = blockIdx.x * 64;
  int t = threadIdx.x, rr = t >> 4, cc = t & 15;
  #pragma unroll
  for (int p = 0; p < 4; p++){
    int r = rr + p * 16;
    float4 v = *(const float4*)(src + (size_t)(r0 + r) * sld + c0 + cc * 4);
    ushort4 o; o.x = f2bf(v.x); o.y = f2bf(v.y); o.z = f2bf(v.z); o.w = f2bf(v.w);
    *(ushort4*)&tile[r][cc * 4] = o;
  }
  __syncthreads();
  #pragma unroll
  for (int p = 0; p < 4; p++){
    int c = rr + p * 16;
    ushort4 o;
    o.x = tile[cc*4+0][c]; o.y = tile[cc*4+1][c]; o.z = tile[cc*4+2][c]; o.w = tile[cc*4+3][c];
    *(ushort4*)(dst + (size_t)(c0 + c) * dld + r0 + cc * 4) = o;
  }
}

// ---------------- transpose (u16 src -> u16 dst) ----------------
__global__ void k_tconv_u16(const u16* __restrict__ src, u16* __restrict__ dst,
                            long sslot, long dslot, int sld, int dld){
  __shared__ u16 tile[64][68];
  src += (long)blockIdx.z * sslot;
  dst += (long)blockIdx.z * dslot;
  int r0 = blockIdx.y * 64, c0 = blockIdx.x * 64;
  int t = threadIdx.x, rr = t >> 4, cc = t & 15;
  #pragma unroll
  for (int p = 0; p < 4; p++){
    int r = rr + p * 16;
    ushort4 v = *(const ushort4*)(src + (size_t)(r0 + r) * sld + c0 + cc * 4);
    *(ushort4*)&tile[r][cc * 4] = v;
  }
  __syncthreads();
  #pragma unroll
  for (int p = 0; p < 4; p++){
    int c = rr + p * 16;
    ushort4 o;
    o.x = tile[cc*4+0][c]; o.y = tile[cc*4+1][c]; o.z = tile[cc*4+2][c]; o.w = tile[cc*4+3][c];
    *(ushort4*)(dst + (size_t)(c0 + c) * dld + r0 + cc * 4) = o;
  }
}

// ---------------- RoPE apply (in-place on bf16 q, k) ----------------
__global__ void k_rope(u16* __restrict__ q, u16* __restrict__ kk,
                       const float* __restrict__ rc, const float* __restrict__ rs){
  int idx = blockIdx.x * 256 + threadIdx.x;     // (t*24 + slot)*32 + i4
  int i4 = idx & 31; int rest = idx >> 5;
  int slot = rest % 24; int t = rest / 24;
  u16* base; float sc;
  if (slot < 16){ base = q + (size_t)t * 4096 + slot * 256; sc = 0.0625f; }
  else { base = kk + (size_t)t * 2048 + (slot - 16) * 256; sc = 1.0f; }
  int i = i4 * 4;
  ushort4 a = *(ushort4*)(base + i);
  ushort4 b = *(ushort4*)(base + i + 128);
  float4 c = *(const float4*)(rc + t * 128 + i);
  float4 s = *(const float4*)(rs + t * 128 + i);
  ushort4 oa, ob; float x1, x2;
  x1 = bf2f(a.x); x2 = bf2f(b.x); oa.x = f2bf((x1*c.x - x2*s.x)*sc); ob.x = f2bf((x2*c.x + x1*s.x)*sc);
  x1 = bf2f(a.y); x2 = bf2f(b.y); oa.y = f2bf((x1*c.y - x2*s.y)*sc); ob.y = f2bf((x2*c.y + x1*s.y)*sc);
  x1 = bf2f(a.z); x2 = bf2f(b.z); oa.z = f2bf((x1*c.z - x2*s.z)*sc); ob.z = f2bf((x2*c.z + x1*s.z)*sc);
  x1 = bf2f(a.w); x2 = bf2f(b.w); oa.w = f2bf((x1*c.w - x2*s.w)*sc); ob.w = f2bf((x2*c.w + x1*s.w)*sc);
  *(ushort4*)(base + i) = oa;
  *(ushort4*)(base + i + 128) = ob;
}

// ---------------- GEMM: C = A(MxK) * B^T(NxK), m97 structure ----------------
// MODE 0: QKV projection (A = xb, B panels = wqT/wkvT, C -> qraw/kraw/vraw bf16)
// MODE 1: out projection (A = enc, B = woT, C -> out f32)
template<int MODE>
__global__ __launch_bounds__(256)
void k_gemm(const u16* __restrict__ A, int Ktot,
            const u16* __restrict__ Bq, const u16* __restrict__ Bkv,
            u16* __restrict__ Cq, u16* __restrict__ Ck, u16* __restrict__ Cv,
            float* __restrict__ Cf)
{
  __shared__ __align__(16) u16 As[128 * 32];
  __shared__ __align__(16) u16 Bs[128 * 32];
  int tid = threadIdx.x;
  int ct = blockIdx.x, mt = blockIdx.y;
  int m0 = mt * 128;
  const u16* Bbase;
  u16* Cb = nullptr; int ldc = 0; long ccol0 = 0;
  if (MODE == 0){
    int slot = ct >> 1;
    long pan = (long)(ct & 1) * 128 * FEAT;
    if (slot < 16){ Bbase = Bq + (long)slot * WSLOT + pan; Cb = Cq; ldc = 4096; ccol0 = (long)ct * 128; }
    else {
      Bbase = Bkv + (long)(slot - 16) * WSLOT + pan;
      if (slot < 24){ Cb = Ck; ccol0 = (long)(ct - 32) * 128; }
      else          { Cb = Cv; ccol0 = (long)(ct - 48) * 128; }
      ldc = 2048;
    }
  } else {
    Bbase = Bq + (long)ct * 128 * 4096; ldc = FEAT; ccol0 = (long)ct * 128;
  }
  const int ld = Ktot;
  int lane = tid & 63, wv = tid >> 6;
  int wm = wv >> 1, wn = wv & 1;
  int l15 = lane & 15, lk = lane >> 4;
  const u16* ga = A + (size_t)(m0 + (tid >> 2)) * ld + (tid & 3) * 8;
  const u16* gb = Bbase + (size_t)(tid >> 2) * ld + (tid & 3) * 8;
  int aoff = (wm * 64 + l15) * 32 + lk * 8;
  int boff = (wn * 64 + l15) * 32 + lk * 8;
  f32x4 acc[4][4];
  #pragma unroll
  for (int i = 0; i < 4; i++)
    #pragma unroll
    for (int j = 0; j < 4; j++)
      acc[i][j] = (f32x4){0.f, 0.f, 0.f, 0.f};
  int nk = Ktot / 32;
  for (int kt = 0; kt < nk; kt++){
    __syncthreads();
    gl_lds16(ga,                    As + tid * 8);
    gl_lds16(ga + 64 * (size_t)ld,  As + 2048 + tid * 8);
    gl_lds16(gb,                    Bs + tid * 8);
    gl_lds16(gb + 64 * (size_t)ld,  Bs + 2048 + tid * 8);
    ga += 32; gb += 32;
    __syncthreads();
    short8 af[4], bfr[4];
    #pragma unroll
    for (int i = 0; i < 4; i++) af[i]  = *(const short8*)(As + aoff + i * 512);
    #pragma unroll
    for (int j = 0; j < 4; j++) bfr[j] = *(const short8*)(Bs + boff + j * 512);
    #pragma unroll
    for (int i = 0; i < 4; i++)
      #pragma unroll
      for (int j = 0; j < 4; j++)
        acc[i][j] = __builtin_amdgcn_mfma_f32_16x16x32_bf16(af[i], bfr[j], acc[i][j], 0, 0, 0);
  }
  #pragma unroll
  for (int i = 0; i < 4; i++)
    #pragma unroll
    for (int j = 0; j < 4; j++)
      #pragma unroll
      for (int r = 0; r < 4; r++){
        int trow = m0 + wm * 64 + i * 16 + lk * 4 + r;
        long tcol = ccol0 + wn * 64 + j * 16 + l15;
        if (MODE == 0) Cb[(size_t)trow * ldc + tcol] = f2bf(acc[i][j][r]);
        else           Cf[(size_t)trow * FEAT + tcol] = acc[i][j][r];
      }
}

// ---------------- fused sliding-window GQA attention ----------------
// grid: head*32 + qtile, 512 threads (8 waves = 4 t-strips x 2 halves)
__global__ __launch_bounds__(512)
void k_attn(const u16* __restrict__ qb, const u16* __restrict__ kb,
            const u16* __restrict__ vt, u16* __restrict__ enc)
{
  __shared__ __align__(16) u16 P[4][16][32];
  __shared__ float Dsum[8][16];
  int tid = threadIdx.x, lane = tid & 63, wv = tid >> 6;
  int strip = wv >> 1, half = wv & 1;
  int head = blockIdx.x >> 5, qt = blockIdx.x & 31;
  int q0 = qt * 64;
  int kvh = head >> 1;
  int l15 = lane & 15, lk = lane >> 4;
  short8 qf[8];
  {
    const u16* qrow = qb + (size_t)(q0 + strip * 16 + l15) * 4096 + head * 256 + lk * 8;
    #pragma unroll
    for (int c = 0; c < 8; c++) qf[c] = *(const short8*)(qrow + c * 32);
  }
  f32x4 acc[8];
  #pragma unroll
  for (int nf = 0; nf < 8; nf++) acc[nf] = (f32x4){0.f, 0.f, 0.f, 0.f};
  float dsum[4] = {0.f, 0.f, 0.f, 0.f};
  int s_lo = q0 - 1023; if (s_lo < 0) s_lo = 0; s_lo &= ~31;
  int s_hi = q0 + 63;
  const u16* kbase = kb + kvh * 256 + lk * 8;
  const u16* vbase = vt + (size_t)kvh * 256 * 2048 + (size_t)(half * 128 + l15) * 2048 + lk * 8;
  for (int s0 = s_lo; s0 <= s_hi; s0 += 32){
    // QK^T for this wave's (t-strip, s-half): 16x16 tile over K=256
    f32x4 sacc = (f32x4){0.f, 0.f, 0.f, 0.f};
    const u16* krow = kbase + (size_t)(s0 + half * 16 + l15) * 2048;
    #pragma unroll
    for (int c = 0; c < 8; c++){
      short8 kf = *(const short8*)(krow + c * 32);
      sacc = __builtin_amdgcn_mfma_f32_16x16x32_bf16(qf[c], kf, sacc, 0, 0, 0);
    }
    // soft-cap + mask + exp (no online max needed: |logit| <= 50)
    int s_el = s0 + half * 16 + l15;
    int tb = q0 + strip * 16 + lk * 4;
    #pragma unroll
    for (int r = 0; r < 4; r++){
      int t = tb + r;
      float z = sacc[r] * 0.02f;                    // S / 50
      z = fminf(fmaxf(z, -20.f), 20.f);
      float e2 = __expf(2.f * z);
      float p = __expf(50.f * (e2 - 1.f) / (e2 + 1.f));
      p = (s_el <= t && s_el > t - 1024) ? p : 0.f;
      dsum[r] += p;
      P[strip][lk * 4 + r][half * 16 + l15] = f2bf(p);
    }
    __syncthreads();
    // PV: A = P(16t x 32s), B = V^T panels (this wave's h-half, 8 x 16 cols)
    short8 pf = *(const short8*)(&P[strip][l15][lk * 8]);
    const u16* vrow = vbase + s0;
    #pragma unroll
    for (int nf = 0; nf < 8; nf++){
      short8 vf = *(const short8*)(vrow + nf * 16 * 2048);
      acc[nf] = __builtin_amdgcn_mfma_f32_16x16x32_bf16(pf, vf, acc[nf], 0, 0, 0);
    }
    __syncthreads();
  }
  // denominator: reduce across the 16 lanes of each row group, then across halves
  #pragma unroll
  for (int r = 0; r < 4; r++){
    float d = dsum[r];
    d += __shfl_xor(d, 1); d += __shfl_xor(d, 2);
    d += __shfl_xor(d, 4); d += __shfl_xor(d, 8);
    dsum[r] = d;
  }
  if (l15 == 0){
    #pragma unroll
    for (int r = 0; r < 4; r++) Dsum[wv][lk * 4 + r] = dsum[r];
  }
  __syncthreads();
  #pragma unroll
  for (int r = 0; r < 4; r++){
    int tl = lk * 4 + r;
    float inv = 1.f / (Dsum[strip * 2][tl] + Dsum[strip * 2 + 1][tl]);
    size_t orow = (size_t)(q0 + strip * 16 + tl) * 4096 + head * 256 + half * 128;
    #pragma unroll
    for (int nf = 0; nf < 8; nf++)
      enc[orow + nf * 16 + l15] = f2bf(acc[nf][r] * inv);
  }
}

extern "C" void kernel_launch(void* const* d_in, const int* in_sizes, int n_in,
                              void* d_out, int out_size, void* d_ws, size_t ws_size,
                              hipStream_t stream)
{
  (void)in_sizes; (void)n_in; (void)out_size; (void)ws_size;
  const float* x   = (const float*)d_in[0];
  const int*   sp  = (const int*)d_in[1];
  const float* wq  = (const float*)d_in[3];
  const float* wkv = (const float*)d_in[4];
  const float* wo  = (const float*)d_in[5];
  float* out = (float*)d_out;
  char* ws = (char*)d_ws;
  // workspace layout (128 MB total)
  u16*  xb   = (u16*)(ws + 0);          // 2048x3584 bf16
  u16*  wqT  = (u16*)(ws + 14680064);   // 16 x 256 x 3584 bf16 (later reused as woT 3584x4096)
  u16*  wkvT = (u16*)(ws + 44040192);   // 16 x 256 x 3584 bf16 (k slots 0-7, v slots 8-15)
  u16*  qb   = (u16*)(ws + 73400320);   // 2048 x 4096 bf16
  u16*  kb   = (u16*)(ws + 90177536);   // 2048 x 2048 bf16
  u16*  vraw = (u16*)(ws + 98566144);   // 2048 x 2048 bf16
  u16*  vt   = (u16*)(ws + 106954752);  // 8 x 256 x 2048 bf16
  u16*  enc  = (u16*)(ws + 115343360);  // 2048 x 4096 bf16
  float* rc  = (float*)(ws + 132120576);
  float* rs  = (float*)(ws + 133169152);

  k_conv_x  <<<7168, 256, 0, stream>>>(x, xb);
  k_rope_tab<<<1024, 256, 0, stream>>>(sp, rc, rs);
  k_tconv_f32<<<dim3(4, 56, 16), 256, 0, stream>>>(wq,  wqT,  WSLOT, WSLOT, 256, 3584);
  k_tconv_f32<<<dim3(4, 56, 16), 256, 0, stream>>>(wkv, wkvT, WSLOT, WSLOT, 256, 3584);
  k_gemm<0> <<<dim3(64, 16), 256, 0, stream>>>(xb, FEAT, wqT, wkvT, qb, kb, vraw, nullptr);
  k_rope    <<<6144, 256, 0, stream>>>(qb, kb, rc, rs);
  k_tconv_u16<<<dim3(4, 32, 8), 256, 0, stream>>>(vraw, vt, 256, 524288, 2048, 2048);
  k_attn    <<<dim3(512), 512, 0, stream>>>(qb, kb, vt, enc);
  k_tconv_f32<<<dim3(56, 4, 16), 256, 0, stream>>>(wo, wqT /*woT*/, WSLOT, 256, 3584, 4096);
  k_gemm<1> <<<dim3(28, 16), 256, 0, stream>>>(enc, 4096, wqT /*woT*/, nullptr,
                                               nullptr, nullptr, nullptr, out);
}

// Round 4
// 664.145 us; speedup vs baseline: 1.1504x; 1.1504x over previous
//
#include <hip/hip_runtime.h>
#include <stdint.h>

typedef unsigned short u16;
typedef __attribute__((ext_vector_type(8))) short short8;
typedef __attribute__((ext_vector_type(4))) float f32x4;
typedef __attribute__((ext_vector_type(16))) float f32x16;

#define SEQ    2048
#define FEAT   3584
#define NHEAD  16
#define HD     256
#define WSLOT  917504  // 3584*256

static __device__ __forceinline__ float bf2f(u16 v){
  union { unsigned u; float f; } x; x.u = ((unsigned)v) << 16; return x.f;
}
static __device__ __forceinline__ u16 f2bf(float f){
  union { float f; unsigned u; } x; x.f = f;
  unsigned r = x.u + 0x7fffu + ((x.u >> 16) & 1u);
  return (u16)(r >> 16);
}
static __device__ __forceinline__ unsigned pk2(float a, float b){
  return (unsigned)f2bf(a) | ((unsigned)f2bf(b) << 16);
}

static __device__ __forceinline__ void gl_lds16(const u16* g, u16* l){
  __builtin_amdgcn_global_load_lds((const __attribute__((address_space(1))) void*)g,
                                   (__attribute__((address_space(3))) void*)l,
                                   16, 0, 0);
}

// ---------------- x f32 -> bf16 ----------------
__global__ void k_conv_x(const float* __restrict__ x, u16* __restrict__ xb){
  int i = (blockIdx.x * 256 + threadIdx.x) * 4;
  float4 v = *(const float4*)(x + i);
  ushort4 o; o.x = f2bf(v.x); o.y = f2bf(v.y); o.z = f2bf(v.z); o.w = f2bf(v.w);
  *(ushort4*)(xb + i) = o;
}

// ---------------- RoPE tables ----------------
__global__ void k_rope_tab(const int* __restrict__ sp, float* __restrict__ rc, float* __restrict__ rs){
  int idx = blockIdx.x * 256 + threadIdx.x;   // t*128 + i
  int t = idx >> 7, i = idx & 127;
  float ts = powf(10000.0f, (float)i * (1.0f / 128.0f));
  float ang = (float)sp[t] / ts;
  float s, c;
  sincosf(ang, &s, &c);
  rc[idx] = c; rs[idx] = s;
}

// ---------------- transpose + convert (f32 src -> bf16 dst, dst[c][r] = src[r][c]) ----------------
__global__ void k_tconv_f32(const float* __restrict__ src, u16* __restrict__ dst,
                            long sslot, long dslot, int sld, int dld){
  __shared__ u16 tile[64][68];
  src += (long)blockIdx.z * sslot;
  dst += (long)blockIdx.z * dslot;
  int r0 = blockIdx.y * 64, c0 = blockIdx.x * 64;
  int t = threadIdx.x, rr = t >> 4, cc = t & 15;
  #pragma unroll
  for (int p = 0; p < 4; p++){
    int r = rr + p * 16;
    float4 v = *(const float4*)(src + (size_t)(r0 + r) * sld + c0 + cc * 4);
    ushort4 o; o.x = f2bf(v.x); o.y = f2bf(v.y); o.z = f2bf(v.z); o.w = f2bf(v.w);
    *(ushort4*)&tile[r][cc * 4] = o;
  }
  __syncthreads();
  #pragma unroll
  for (int p = 0; p < 4; p++){
    int c = rr + p * 16;
    ushort4 o;
    o.x = tile[cc*4+0][c]; o.y = tile[cc*4+1][c]; o.z = tile[cc*4+2][c]; o.w = tile[cc*4+3][c];
    *(ushort4*)(dst + (size_t)(c0 + c) * dld + r0 + cc * 4) = o;
  }
}

// ---------------- transpose (u16 src -> u16 dst) ----------------
__global__ void k_tconv_u16(const u16* __restrict__ src, u16* __restrict__ dst,
                            long sslot, long dslot, int sld, int dld){
  __shared__ u16 tile[64][68];
  src += (long)blockIdx.z * sslot;
  dst += (long)blockIdx.z * dslot;
  int r0 = blockIdx.y * 64, c0 = blockIdx.x * 64;
  int t = threadIdx.x, rr = t >> 4, cc = t & 15;
  #pragma unroll
  for (int p = 0; p < 4; p++){
    int r = rr + p * 16;
    ushort4 v = *(const ushort4*)(src + (size_t)(r0 + r) * sld + c0 + cc * 4);
    *(ushort4*)&tile[r][cc * 4] = v;
  }
  __syncthreads();
  #pragma unroll
  for (int p = 0; p < 4; p++){
    int c = rr + p * 16;
    ushort4 o;
    o.x = tile[cc*4+0][c]; o.y = tile[cc*4+1][c]; o.z = tile[cc*4+2][c]; o.w = tile[cc*4+3][c];
    *(ushort4*)(dst + (size_t)(c0 + c) * dld + r0 + cc * 4) = o;
  }
}

// ---------------- RoPE apply (in-place on bf16 q, k) ----------------
__global__ void k_rope(u16* __restrict__ q, u16* __restrict__ kk,
                       const float* __restrict__ rc, const float* __restrict__ rs){
  int idx = blockIdx.x * 256 + threadIdx.x;     // (t*24 + slot)*32 + i4
  int i4 = idx & 31; int rest = idx >> 5;
  int slot = rest % 24; int t = rest / 24;
  u16* base; float sc;
  if (slot < 16){ base = q + (size_t)t * 4096 + slot * 256; sc = 0.0625f; }
  else { base = kk + (size_t)t * 2048 + (slot - 16) * 256; sc = 1.0f; }
  int i = i4 * 4;
  ushort4 a = *(ushort4*)(base + i);
  ushort4 b = *(ushort4*)(base + i + 128);
  float4 c = *(const float4*)(rc + t * 128 + i);
  float4 s = *(const float4*)(rs + t * 128 + i);
  ushort4 oa, ob; float x1, x2;
  x1 = bf2f(a.x); x2 = bf2f(b.x); oa.x = f2bf((x1*c.x - x2*s.x)*sc); ob.x = f2bf((x2*c.x + x1*s.x)*sc);
  x1 = bf2f(a.y); x2 = bf2f(b.y); oa.y = f2bf((x1*c.y - x2*s.y)*sc); ob.y = f2bf((x2*c.y + x1*s.y)*sc);
  x1 = bf2f(a.z); x2 = bf2f(b.z); oa.z = f2bf((x1*c.z - x2*s.z)*sc); ob.z = f2bf((x2*c.z + x1*s.z)*sc);
  x1 = bf2f(a.w); x2 = bf2f(b.w); oa.w = f2bf((x1*c.w - x2*s.w)*sc); ob.w = f2bf((x2*c.w + x1*s.w)*sc);
  *(ushort4*)(base + i) = oa;
  *(ushort4*)(base + i + 128) = ob;
}

// ---------------- GEMM: C = A(MxK) * B^T(NxK), m97 structure ----------------
template<int MODE>
__global__ __launch_bounds__(256)
void k_gemm(const u16* __restrict__ A, int Ktot,
            const u16* __restrict__ Bq, const u16* __restrict__ Bkv,
            u16* __restrict__ Cq, u16* __restrict__ Ck, u16* __restrict__ Cv,
            float* __restrict__ Cf)
{
  __shared__ __align__(16) u16 As[128 * 32];
  __shared__ __align__(16) u16 Bs[128 * 32];
  int tid = threadIdx.x;
  int ct = blockIdx.x, mt = blockIdx.y;
  int m0 = mt * 128;
  const u16* Bbase;
  u16* Cb = nullptr; int ldc = 0; long ccol0 = 0;
  if (MODE == 0){
    int slot = ct >> 1;
    long pan = (long)(ct & 1) * 128 * FEAT;
    if (slot < 16){ Bbase = Bq + (long)slot * WSLOT + pan; Cb = Cq; ldc = 4096; ccol0 = (long)ct * 128; }
    else {
      Bbase = Bkv + (long)(slot - 16) * WSLOT + pan;
      if (slot < 24){ Cb = Ck; ccol0 = (long)(ct - 32) * 128; }
      else          { Cb = Cv; ccol0 = (long)(ct - 48) * 128; }
      ldc = 2048;
    }
  } else {
    Bbase = Bq + (long)ct * 128 * 4096; ldc = FEAT; ccol0 = (long)ct * 128;
  }
  const int ld = Ktot;
  int lane = tid & 63, wv = tid >> 6;
  int wm = wv >> 1, wn = wv & 1;
  int l15 = lane & 15, lk = lane >> 4;
  const u16* ga = A + (size_t)(m0 + (tid >> 2)) * ld + (tid & 3) * 8;
  const u16* gb = Bbase + (size_t)(tid >> 2) * ld + (tid & 3) * 8;
  int aoff = (wm * 64 + l15) * 32 + lk * 8;
  int boff = (wn * 64 + l15) * 32 + lk * 8;
  f32x4 acc[4][4];
  #pragma unroll
  for (int i = 0; i < 4; i++)
    #pragma unroll
    for (int j = 0; j < 4; j++)
      acc[i][j] = (f32x4){0.f, 0.f, 0.f, 0.f};
  int nk = Ktot / 32;
  for (int kt = 0; kt < nk; kt++){
    __syncthreads();
    gl_lds16(ga,                    As + tid * 8);
    gl_lds16(ga + 64 * (size_t)ld,  As + 2048 + tid * 8);
    gl_lds16(gb,                    Bs + tid * 8);
    gl_lds16(gb + 64 * (size_t)ld,  Bs + 2048 + tid * 8);
    ga += 32; gb += 32;
    __syncthreads();
    short8 af[4], bfr[4];
    #pragma unroll
    for (int i = 0; i < 4; i++) af[i]  = *(const short8*)(As + aoff + i * 512);
    #pragma unroll
    for (int j = 0; j < 4; j++) bfr[j] = *(const short8*)(Bs + boff + j * 512);
    #pragma unroll
    for (int i = 0; i < 4; i++)
      #pragma unroll
      for (int j = 0; j < 4; j++)
        acc[i][j] = __builtin_amdgcn_mfma_f32_16x16x32_bf16(af[i], bfr[j], acc[i][j], 0, 0, 0);
  }
  #pragma unroll
  for (int i = 0; i < 4; i++)
    #pragma unroll
    for (int j = 0; j < 4; j++)
      #pragma unroll
      for (int r = 0; r < 4; r++){
        int trow = m0 + wm * 64 + i * 16 + lk * 4 + r;
        long tcol = ccol0 + wn * 64 + j * 16 + l15;
        if (MODE == 0) Cb[(size_t)trow * ldc + tcol] = f2bf(acc[i][j][r]);
        else           Cf[(size_t)trow * FEAT + tcol] = acc[i][j][r];
      }
}

// ---------------- fused sliding-window GQA attention, wave-independent ----------------
// grid 256 blocks x 512 thr. block: kvh = bx&7 (XCD-pinned), qpair = bx>>3.
// 8 waves = {2 heads x 2 qtiles} x 2 s-splits. Each wave: 32 q-rows, 32x32x16 MFMA,
// swapped QK^T (lane owns P column t=lane&31), in-register softcap, no loop barriers.
// Denominator: dsum is indexed by lane (t=q0+l31); PV output rows are indexed by
// register (trow(r)) -> redistribute 1/dsum through drow[] LDS before the final write.
__global__ __launch_bounds__(512, 2)
void k_attn(const u16* __restrict__ qb, const u16* __restrict__ kb,
            const u16* __restrict__ vt, u16* __restrict__ enc)
{
  __shared__ float cmb[4][64][64];   // 64 KB combine buffer
  __shared__ float drow[4][32];      // per-unit 1/denominator, indexed by t-row
  int tid = threadIdx.x;
  int wv = tid >> 6, lane = tid & 63;
  int unit = wv & 3, split = wv >> 2;
  int l31 = lane & 31, hi = lane >> 5;
  int kvh = blockIdx.x & 7, qp = blockIdx.x >> 3;
  int head = kvh * 2 + (unit >> 1);
  int q0 = qp * 64 + (unit & 1) * 32;
  int t = q0 + l31;

  // Q fragments (B-operand): lane holds col t=lane&31, k = kk*16 + hi*8 + e
  short8 qf[16];
  {
    const u16* qrow = qb + (size_t)t * 4096 + head * 256 + hi * 8;
    #pragma unroll
    for (int kk = 0; kk < 16; kk++) qf[kk] = *(const short8*)(qrow + kk * 16);
  }
  f32x16 acc[8];
  #pragma unroll
  for (int nf = 0; nf < 8; nf++)
    #pragma unroll
    for (int r = 0; r < 16; r++) acc[nf][r] = 0.f;
  float dsum = 0.f;

  // s-tile range for this q-tile, split between the two s-split waves
  int tl = q0 > 1023 ? (q0 - 1023) >> 5 : 0;
  int th = (q0 + 31) >> 5;
  int hcnt = (th - tl + 2) >> 1;
  int ti0 = split ? tl + hcnt : tl;
  int ti1 = split ? th + 1 : tl + hcnt;

  const u16* kcol = kb + (size_t)kvh * 256 + hi * 8;
  const u16* vcol = vt + (size_t)kvh * 524288 + (size_t)l31 * 2048 + hi * 8;

  for (int ti = ti0; ti < ti1; ti++){
    int s0 = ti << 5;
    // QK^T swapped: A = K rows (s = lane&31), B = Q cols (t) -> S^T[s][t]
    const u16* kr = kcol + (size_t)(s0 + l31) * 2048;
    f32x16 sacc;
    #pragma unroll
    for (int r = 0; r < 16; r++) sacc[r] = 0.f;
    #pragma unroll
    for (int kk = 0; kk < 16; kk++){
      short8 kf = *(const short8*)(kr + kk * 16);
      sacc = __builtin_amdgcn_mfma_f32_32x32x16_bf16(kf, qf[kk], sacc, 0, 0, 0);
    }
    // softcap + mask + exp (soft-cap bounds |logit|<=50: no running max needed)
    float p[16];
    #pragma unroll
    for (int r = 0; r < 16; r++){
      int s = s0 + (r & 3) + 8 * (r >> 2) + 4 * hi;
      float z = sacc[r] * 0.02f;
      z = fminf(fmaxf(z, -20.f), 20.f);
      float e2 = __expf(2.f * z);
      float pw = __expf(50.f * (e2 - 1.f) / (e2 + 1.f));
      pw = (s <= t && s > t - 1024) ? pw : 0.f;
      dsum += pw;
      p[r] = pw;
    }
    // P -> PV A-fragment (row t = lane&31, k = s): cvt-pack + cross-half exchange
    #pragma unroll
    for (int ks = 0; ks < 2; ks++){
      unsigned A0 = pk2(p[8*ks+0], p[8*ks+1]);
      unsigned A1 = pk2(p[8*ks+2], p[8*ks+3]);
      unsigned B0 = pk2(p[8*ks+4], p[8*ks+5]);
      unsigned B1 = pk2(p[8*ks+6], p[8*ks+7]);
      unsigned xA0 = (unsigned)__shfl_xor((int)A0, 32);
      unsigned xA1 = (unsigned)__shfl_xor((int)A1, 32);
      unsigned xB0 = (unsigned)__shfl_xor((int)B0, 32);
      unsigned xB1 = (unsigned)__shfl_xor((int)B1, 32);
      union { unsigned u[4]; short8 v; } pa;
      pa.u[0] = hi ? xB0 : A0;
      pa.u[1] = hi ? xB1 : A1;
      pa.u[2] = hi ? B0 : xA0;
      pa.u[3] = hi ? B1 : xA1;
      const u16* vr = vcol + s0 + ks * 16;
      #pragma unroll
      for (int nf = 0; nf < 8; nf++){
        short8 vf = *(const short8*)(vr + (size_t)nf * 32 * 2048);
        acc[nf] = __builtin_amdgcn_mfma_f32_32x32x16_bf16(pa.v, vf, acc[nf], 0, 0, 0);
      }
    }
  }

  // combine the two s-splits (only cross-wave sync in the kernel)
  if (split) cmb[unit][0][lane] = dsum;
  __syncthreads();
  if (!split){
    dsum += cmb[unit][0][lane];
    dsum += __shfl_xor(dsum, 32);         // combine hi halves -> full denom for t=q0+l31
    if (hi == 0) drow[unit][l31] = 1.f / dsum;
  }
  __syncthreads();
  #pragma unroll
  for (int hf = 0; hf < 2; hf++){
    if (split){
      #pragma unroll
      for (int nf = 0; nf < 4; nf++)
        #pragma unroll
        for (int r = 0; r < 16; r++)
          cmb[unit][nf * 16 + r][lane] = acc[hf * 4 + nf][r];
    }
    __syncthreads();
    if (!split){
      #pragma unroll
      for (int nf = 0; nf < 4; nf++)
        #pragma unroll
        for (int r = 0; r < 16; r++)
          acc[hf * 4 + nf][r] += cmb[unit][nf * 16 + r][lane];
    }
    __syncthreads();
  }
  if (!split){
    #pragma unroll
    for (int nf = 0; nf < 8; nf++)
      #pragma unroll
      for (int r = 0; r < 16; r++){
        int trow = (r & 3) + 8 * (r >> 2) + 4 * hi;
        float inv = drow[unit][trow];
        enc[(size_t)(q0 + trow) * 4096 + head * 256 + nf * 32 + l31] = f2bf(acc[nf][r] * inv);
      }
  }
}

extern "C" void kernel_launch(void* const* d_in, const int* in_sizes, int n_in,
                              void* d_out, int out_size, void* d_ws, size_t ws_size,
                              hipStream_t stream)
{
  (void)in_sizes; (void)n_in; (void)out_size; (void)ws_size;
  const float* x   = (const float*)d_in[0];
  const int*   sp  = (const int*)d_in[1];
  const float* wq  = (const float*)d_in[3];
  const float* wkv = (const float*)d_in[4];
  const float* wo  = (const float*)d_in[5];
  float* out = (float*)d_out;
  char* ws = (char*)d_ws;
  u16*  xb   = (u16*)(ws + 0);          // 2048x3584 bf16
  u16*  wqT  = (u16*)(ws + 14680064);   // 16 x 256 x 3584 bf16 (later reused as woT)
  u16*  wkvT = (u16*)(ws + 44040192);   // 16 x 256 x 3584 bf16
  u16*  qb   = (u16*)(ws + 73400320);   // 2048 x 4096 bf16
  u16*  kb   = (u16*)(ws + 90177536);   // 2048 x 2048 bf16
  u16*  vraw = (u16*)(ws + 98566144);   // 2048 x 2048 bf16
  u16*  vt   = (u16*)(ws + 106954752);  // 8 x 256 x 2048 bf16
  u16*  enc  = (u16*)(ws + 115343360);  // 2048 x 4096 bf16
  float* rc  = (float*)(ws + 132120576);
  float* rs  = (float*)(ws + 133169152);

  k_conv_x  <<<7168, 256, 0, stream>>>(x, xb);
  k_rope_tab<<<1024, 256, 0, stream>>>(sp, rc, rs);
  k_tconv_f32<<<dim3(4, 56, 16), 256, 0, stream>>>(wq,  wqT,  WSLOT, WSLOT, 256, 3584);
  k_tconv_f32<<<dim3(4, 56, 16), 256, 0, stream>>>(wkv, wkvT, WSLOT, WSLOT, 256, 3584);
  k_gemm<0> <<<dim3(64, 16), 256, 0, stream>>>(xb, FEAT, wqT, wkvT, qb, kb, vraw, nullptr);
  k_rope    <<<6144, 256, 0, stream>>>(qb, kb, rc, rs);
  k_tconv_u16<<<dim3(4, 32, 8), 256, 0, stream>>>(vraw, vt, 256, 524288, 2048, 2048);
  k_attn    <<<dim3(256), 512, 0, stream>>>(qb, kb, vt, enc);
  k_tconv_f32<<<dim3(56, 4, 16), 256, 0, stream>>>(wo, wqT /*woT*/, WSLOT, 256, 3584, 4096);
  k_gemm<1> <<<dim3(28, 16), 256, 0, stream>>>(enc, 4096, wqT /*woT*/, nullptr,
                                               nullptr, nullptr, nullptr, out);
}